// Round 5
// baseline (2057.299 us; speedup 1.0000x reference)
//
#include <hip/hip_runtime.h>
#include <hip/hip_bf16.h>

#define N_GRAPHS 256

typedef __attribute__((ext_vector_type(8))) short short8;
typedef __attribute__((ext_vector_type(4))) float f32x4;

__device__ __forceinline__ float lrelu(float x){ return x > 0.f ? x : 0.2f*x; }
__device__ __forceinline__ unsigned short f2bf(float f){
  unsigned u = __float_as_uint(f);
  unsigned r = u + 0x7fffu + ((u >> 16) & 1u);
  return (unsigned short)(r >> 16);
}
__device__ __forceinline__ float bf2f(unsigned short h){ return __uint_as_float(((unsigned)h) << 16); }

// ---- precompute W_gat split-bf16 fragment buffer ----------------------------
// Bf element q = slot*512 + lane*8 + j ; slot = ((s*8+f)*2+p)
// value = part-p of W[32s + 8*(lane>>4) + j][16f + (lane&15)]
__global__ void k_prepW(const float* __restrict__ W, unsigned short* __restrict__ Bf){
  int q = blockIdx.x * 256 + threadIdx.x;          // 0..32767
  int j = q & 7, lane = (q >> 3) & 63;
  int rest = q >> 9;                               // 0..63
  int p = rest & 1, f = (rest >> 1) & 7, s = rest >> 4;
  int k = 32 * s + 8 * (lane >> 4) + j;
  int n = 16 * f + (lane & 15);
  float w = W[k * 128 + n];
  unsigned short hi = f2bf(w);
  Bf[q] = p ? f2bf(w - bf2f(hi)) : hi;
}

// ---- h = x @ W_gat via MFMA bf16x3; fused a_s/a_d; h written as bf16 --------
__global__ __launch_bounds__(256) void k_gemm(const float* __restrict__ X, const unsigned short* __restrict__ Bf,
                                              const float* __restrict__ att_src, const float* __restrict__ att_dst,
                                              unsigned short* __restrict__ Hb, float* __restrict__ a_s,
                                              float* __restrict__ a_d, int N){
  int w = threadIdx.x >> 6, l = threadIdx.x & 63;
  int r0 = blockIdx.x * 64 + w * 16;
  int lrow = l & 15, lk = l >> 4;
  int rload = min(r0 + lrow, N - 1);
  const short8* B8 = (const short8*)Bf;
  f32x4 acc[8];
#pragma unroll
  for (int f = 0; f < 8; ++f) acc[f] = (f32x4){0.f, 0.f, 0.f, 0.f};

#pragma unroll
  for (int s = 0; s < 4; ++s){
    const float* xp = X + (size_t)rload * 128 + 32 * s + 8 * lk;
    float4 xa = *(const float4*)xp;
    float4 xb = *(const float4*)(xp + 4);
    float xv[8] = {xa.x, xa.y, xa.z, xa.w, xb.x, xb.y, xb.z, xb.w};
    short8 ah, al;
#pragma unroll
    for (int j = 0; j < 8; ++j){
      unsigned short h = f2bf(xv[j]);
      ah[j] = (short)h;
      al[j] = (short)f2bf(xv[j] - bf2f(h));
    }
#pragma unroll
    for (int f = 0; f < 8; ++f){
      short8 bh = B8[((s * 8 + f) * 2 + 0) * 64 + l];
      short8 bl = B8[((s * 8 + f) * 2 + 1) * 64 + l];
      acc[f] = __builtin_amdgcn_mfma_f32_16x16x32_bf16(ah, bh, acc[f], 0, 0, 0);
      acc[f] = __builtin_amdgcn_mfma_f32_16x16x32_bf16(al, bh, acc[f], 0, 0, 0);
      acc[f] = __builtin_amdgcn_mfma_f32_16x16x32_bf16(ah, bl, acc[f], 0, 0, 0);
    }
  }
  // epilogue: C layout col = lane&15, row = 4*(lane>>4)+reg
  float avs[8], avd[8];
#pragma unroll
  for (int f = 0; f < 8; ++f){
    avs[f] = att_src[16 * f + lrow];
    avd[f] = att_dst[16 * f + lrow];
  }
#pragma unroll
  for (int reg = 0; reg < 4; ++reg){
    int row = r0 + 4 * lk + reg;
    if (row < N){
#pragma unroll
      for (int f = 0; f < 8; ++f) Hb[(size_t)row * 128 + 16 * f + lrow] = f2bf(acc[f][reg]);
    }
    float ps0 = 0.f, ps1 = 0.f, pd0 = 0.f, pd1 = 0.f;
#pragma unroll
    for (int f = 0; f < 4; ++f){ ps0 += acc[f][reg] * avs[f]; pd0 += acc[f][reg] * avd[f]; }
#pragma unroll
    for (int f = 4; f < 8; ++f){ ps1 += acc[f][reg] * avs[f]; pd1 += acc[f][reg] * avd[f]; }
#pragma unroll
    for (int off = 1; off < 16; off <<= 1){
      ps0 += __shfl_xor(ps0, off); ps1 += __shfl_xor(ps1, off);
      pd0 += __shfl_xor(pd0, off); pd1 += __shfl_xor(pd1, off);
    }
    if (lrow == 0 && row < N){
      a_s[2 * row] = ps0; a_s[2 * row + 1] = ps1;
      a_d[2 * row] = pd0; a_d[2 * row + 1] = pd1;
    }
  }
}

// ---- dst-CSR build ----------------------------------------------------------
__global__ void k_hist(const int* __restrict__ ei, int* __restrict__ pd, int E){
  int i = blockIdx.x * 256 + threadIdx.x;
  if (i >= E) return;
  atomicAdd(&pd[ei[E + i] + 1], 1);
}

__global__ __launch_bounds__(1024) void k_scan(int* __restrict__ p, int* __restrict__ c, int N){
  __shared__ int sums[1024];
  int t = threadIdx.x;
  int M = N + 1;
  int C = (M + 1023) >> 10;
  int lo = t * C, hi = min(lo + C, M);
  int s = 0;
  for (int i = lo; i < hi; i++) s += p[i];
  sums[t] = s;
  __syncthreads();
  for (int off = 1; off < 1024; off <<= 1){
    int v = (t >= off) ? sums[t - off] : 0;
    __syncthreads();
    sums[t] += v;
    __syncthreads();
  }
  int pre = (t == 0) ? 0 : sums[t - 1];
  for (int i = lo; i < hi; i++){
    pre += p[i];
    p[i] = pre;               // p[i] = start offset of node i ; p[N] = E
    if (i < N) c[i] = pre;    // cursor = start of node i
  }
}

__global__ void k_fill(const int* __restrict__ ei, int* __restrict__ cur, int* __restrict__ adj, int E){
  int i = blockIdx.x * 256 + threadIdx.x;
  if (i >= E) return;
  int s = ei[i], d = ei[E + i];
  int p = atomicAdd(&cur[d], 1);
  adj[p] = s;
}

// ---- per-dst softmax aggregation, bf16 h, readlane broadcast ---------------
__global__ __launch_bounds__(256) void k_agg(const int* __restrict__ ptr, const int* __restrict__ adj,
                                             const unsigned* __restrict__ Hu,
                                             const float* __restrict__ a_s, const float* __restrict__ a_d,
                                             float* __restrict__ nf, int N){
  int wid = (blockIdx.x * blockDim.x + threadIdx.x) >> 6;
  int l = threadIdx.x & 63;
  if (wid >= N) return;
  int n = wid;
  float2 adn = *(const float2*)&a_d[2 * n];
  float2 asn = *(const float2*)&a_s[2 * n];
  float e0 = lrelu(asn.x + adn.x), e1 = lrelu(asn.y + adn.y);   // self-loop
  int beg = ptr[n], end = ptr[n + 1];
  float lm0 = e0, lm1 = e1;
  for (int i = beg + l; i < end; i += 64){
    int s = adj[i];
    float2 a2 = *(const float2*)&a_s[2 * s];
    lm0 = fmaxf(lm0, lrelu(a2.x + adn.x));
    lm1 = fmaxf(lm1, lrelu(a2.y + adn.y));
  }
#pragma unroll
  for (int off = 32; off >= 1; off >>= 1){
    lm0 = fmaxf(lm0, __shfl_xor(lm0, off));
    lm1 = fmaxf(lm1, __shfl_xor(lm1, off));
  }
  float w0s = __expf(e0 - lm0), w1s = __expf(e1 - lm1);
  unsigned hv = Hu[(size_t)n * 64 + l];
  float wsel = (l < 32) ? w0s : w1s;
  float accA = wsel * bf2f((unsigned short)(hv & 0xffffu));
  float accB = wsel * bf2f((unsigned short)(hv >> 16));
  float dden0 = 0.f, dden1 = 0.f;
  for (int base = beg; base < end; base += 64){
    int idx = base + l;
    int cl = min(end - base, 64);
    int s = adj[min(idx, end - 1)];
    float2 a2 = *(const float2*)&a_s[2 * s];
    float w0 = 0.f, w1 = 0.f;
    if (idx < end){
      w0 = __expf(lrelu(a2.x + adn.x) - lm0);
      w1 = __expf(lrelu(a2.y + adn.y) - lm1);
    }
    dden0 += w0; dden1 += w1;
    int w0i = __float_as_int(w0), w1i = __float_as_int(w1);
#pragma unroll 4
    for (int j = 0; j < cl; ++j){
      int sj = __builtin_amdgcn_readlane(s, j);
      float wj0 = __int_as_float(__builtin_amdgcn_readlane(w0i, j));
      float wj1 = __int_as_float(__builtin_amdgcn_readlane(w1i, j));
      unsigned hvj = Hu[(size_t)sj * 64 + l];
      float wj = (l < 32) ? wj0 : wj1;
      accA += wj * bf2f((unsigned short)(hvj & 0xffffu));
      accB += wj * bf2f((unsigned short)(hvj >> 16));
    }
  }
#pragma unroll
  for (int off = 32; off >= 1; off >>= 1){
    dden0 += __shfl_xor(dden0, off);
    dden1 += __shfl_xor(dden1, off);
  }
  float den = (l < 32) ? (dden0 + w0s) : (dden1 + w1s);
  float2 o; o.x = accA / den; o.y = accB / den;
  *(float2*)&nf[(size_t)n * 128 + 2 * l] = o;
}

// ---- pooled edge_attr sums per graph (block partials in LDS) ---------------
__global__ __launch_bounds__(256) void k_Spool(const int* __restrict__ ei, const float* __restrict__ ea,
                                               const int* __restrict__ batch, float* __restrict__ part, int E){
  __shared__ float loc[256 * 33];
  int t = threadIdx.x;
  for (int i = t; i < 256 * 33; i += 256) loc[i] = 0.f;
  __syncthreads();
  int l = t & 63, wv = t >> 6;
  int gw = blockIdx.x * 4 + wv;                 // 0..511
  int per = (E + 511) / 512;
  int b0 = gw * per, b1 = min(b0 + per, E);
  int d = l & 31;
  for (int e = b0 + (l >> 5); e < b1; e += 2){
    int src = ei[e];
    int g = batch[src];
    float v = ea[(size_t)e * 32 + d];
    atomicAdd(&loc[g * 33 + d], v);
    if (d == 0) atomicAdd(&loc[g * 33 + 32], 1.0f);
  }
  __syncthreads();
  float* dst = part + (size_t)blockIdx.x * (256 * 33);
  for (int i = t; i < 256 * 33; i += 256) dst[i] = loc[i];
}

__global__ void k_Sred(const float* __restrict__ part, float* __restrict__ pS, float* __restrict__ Eg){
  int g = blockIdx.x, t = threadIdx.x;   // 64 threads
  if (t >= 33) return;
  float s = 0.f;
  for (int b = 0; b < 128; ++b) s += part[(size_t)b * (256 * 33) + g * 33 + t];
  if (t < 32) pS[g * 32 + t] = s;
  else Eg[g] = s;
}

// ---- graph boundaries (batch sorted) ---------------------------------------
__global__ void k_gstart(const int* __restrict__ batch, int* __restrict__ gstart, int N, int G){
  int g = threadIdx.x;
  if (g > G) return;
  int lo = 0, hi = N;
  while (lo < hi){
    int mid = (lo + hi) >> 1;
    if (batch[mid] < g) lo = mid + 1; else hi = mid;
  }
  gstart[g] = lo;
}

// ---- fused pool + MLP head --------------------------------------------------
__global__ __launch_bounds__(128) void k_poolhead(const int* __restrict__ gstart, const float* __restrict__ nf,
                                                  const float* __restrict__ pS, const float* __restrict__ Eg,
                                                  const float* __restrict__ b_gat, const float* __restrict__ W_edge,
                                                  const float* __restrict__ b_edge,
                                                  const float* __restrict__ W1, const float* __restrict__ b1,
                                                  const float* __restrict__ W2, const float* __restrict__ b2,
                                                  const float* __restrict__ W3, const float* __restrict__ b3,
                                                  float* __restrict__ out){
  __shared__ float comb[128];
  __shared__ float z1[100];
  __shared__ float z2[32];
  int g = blockIdx.x, t = threadIdx.x;
  int s0 = gstart[g], s1 = gstart[g + 1];
  int cnt = s1 - s0;
  float pool = 0.f;
  for (int n = s0; n < s1; ++n) pool += nf[(size_t)n * 128 + t];
  float dot = 0.f;
#pragma unroll
  for (int k = 0; k < 32; ++k) dot += pS[g * 32 + k] * W_edge[k * 128 + t];
  comb[t] = pool + (float)cnt * b_gat[t] + Eg[g] * b_edge[t] + dot;
  __syncthreads();
  if (t < 100){
    float z = b1[t];
    for (int k = 0; k < 128; ++k) z += comb[k] * W1[k * 100 + t];
    z1[t] = fmaxf(z, 0.f);
  }
  __syncthreads();
  if (t < 25){
    float z = b2[t];
    for (int k = 0; k < 100; ++k) z += z1[k] * W2[k * 25 + t];
    z2[t] = fmaxf(z, 0.f);
  }
  __syncthreads();
  if (t < 2){
    float z = b3[t];
    for (int k = 0; k < 25; ++k) z += z2[k] * W3[k * 2 + t];
    out[g * 2 + t] = z;
  }
}

extern "C" void kernel_launch(void* const* d_in, const int* in_sizes, int n_in,
                              void* d_out, int out_size, void* d_ws, size_t ws_size,
                              hipStream_t stream) {
  const float* x       = (const float*)d_in[0];
  const int*   ei      = (const int*)d_in[1];
  const float* ea      = (const float*)d_in[2];
  const int*   batch   = (const int*)d_in[3];
  const float* W_gat   = (const float*)d_in[4];
  const float* att_src = (const float*)d_in[5];
  const float* att_dst = (const float*)d_in[6];
  const float* b_gat   = (const float*)d_in[7];
  const float* W_edge  = (const float*)d_in[8];
  const float* b_edge  = (const float*)d_in[9];
  const float* W1 = (const float*)d_in[10];
  const float* b1 = (const float*)d_in[11];
  const float* W2 = (const float*)d_in[12];
  const float* b2 = (const float*)d_in[13];
  const float* W3 = (const float*)d_in[14];
  const float* b3 = (const float*)d_in[15];

  int N = in_sizes[3];        // 50000
  int E = in_sizes[1] / 2;    // 1600000
  int G = N_GRAPHS;

  float* ws = (float*)d_ws;
  size_t o = 0;
  unsigned short* Hb = (unsigned short*)(ws + o); o += (size_t)N * 64;   // N*128 bf16
  float* a_s       = ws + o; o += (size_t)N * 2;
  float* a_d       = ws + o; o += (size_t)N * 2;
  float* nf        = ws + o; o += (size_t)N * 128;
  unsigned short* Bf = (unsigned short*)(ws + o); o += 16384;            // 32768 bf16
  int* ptr_dst     = (int*)(ws + o); o += (size_t)(N + 1);
  int* cur_dst     = (int*)(ws + o); o += (size_t)N + 1;
  int* adj         = (int*)(ws + o); o += (size_t)E;
  float* part      = ws + o; o += (size_t)128 * 256 * 33;
  float* pS        = ws + o; o += (size_t)G * 32;
  float* Eg        = ws + o; o += (size_t)G;
  int* gstart      = (int*)(ws + o); o += (size_t)(G + 1);

  hipMemsetAsync(ptr_dst, 0, (N + 1) * sizeof(int), stream);

  k_prepW<<<128, 256, 0, stream>>>(W_gat, Bf);
  k_gemm<<<(N + 63) / 64, 256, 0, stream>>>(x, Bf, att_src, att_dst, Hb, a_s, a_d, N);
  k_hist<<<(E + 255) / 256, 256, 0, stream>>>(ei, ptr_dst, E);
  k_scan<<<1, 1024, 0, stream>>>(ptr_dst, cur_dst, N);
  k_fill<<<(E + 255) / 256, 256, 0, stream>>>(ei, cur_dst, adj, E);
  k_agg<<<(N + 3) / 4, 256, 0, stream>>>(ptr_dst, adj, (const unsigned*)Hb, a_s, a_d, nf, N);
  k_Spool<<<128, 256, 0, stream>>>(ei, ea, batch, part, E);
  k_Sred<<<G, 64, 0, stream>>>(part, pS, Eg);
  k_gstart<<<1, 512, 0, stream>>>(batch, gstart, N, G);
  k_poolhead<<<G, 128, 0, stream>>>(gstart, nf, pS, Eg, b_gat, W_edge, b_edge,
                                    W1, b1, W2, b2, W3, b3, (float*)d_out);
}

// Round 8
// 1073.216 us; speedup vs baseline: 1.9169x; 1.9169x over previous
//
#include <hip/hip_runtime.h>
#include <hip/hip_bf16.h>

#define N_GRAPHS 256
#define SP_BLOCKS 512
#define SP_WAVES 16            // waves per k_Spool block (1024 threads)

typedef __attribute__((ext_vector_type(8))) short short8;
typedef __attribute__((ext_vector_type(4))) float f32x4;

__device__ __forceinline__ float lrelu(float x){ return x > 0.f ? x : 0.2f*x; }
__device__ __forceinline__ unsigned short f2bf(float f){
  unsigned u = __float_as_uint(f);
  unsigned r = u + 0x7fffu + ((u >> 16) & 1u);
  return (unsigned short)(r >> 16);
}
__device__ __forceinline__ float bf2f(unsigned short h){ return __uint_as_float(((unsigned)h) << 16); }

// ---- precompute W_gat split-bf16 fragment buffer ----------------------------
__global__ void k_prepW(const float* __restrict__ W, unsigned short* __restrict__ Bf){
  int q = blockIdx.x * 256 + threadIdx.x;          // 0..32767
  int j = q & 7, lane = (q >> 3) & 63;
  int rest = q >> 9;                               // 0..63
  int p = rest & 1, f = (rest >> 1) & 7, s = rest >> 4;
  int k = 32 * s + 8 * (lane >> 4) + j;
  int n = 16 * f + (lane & 15);
  float w = W[k * 128 + n];
  unsigned short hi = f2bf(w);
  Bf[q] = p ? f2bf(w - bf2f(hi)) : hi;
}

// ---- h = x @ W_gat via MFMA bf16x3; fused a_s/a_d; h written as bf16 --------
__global__ __launch_bounds__(256) void k_gemm(const float* __restrict__ X, const unsigned short* __restrict__ Bf,
                                              const float* __restrict__ att_src, const float* __restrict__ att_dst,
                                              unsigned short* __restrict__ Hb, float* __restrict__ a_s,
                                              float* __restrict__ a_d, int N){
  int w = threadIdx.x >> 6, l = threadIdx.x & 63;
  int r0 = blockIdx.x * 64 + w * 16;
  int lrow = l & 15, lk = l >> 4;
  int rload = min(r0 + lrow, N - 1);
  const short8* B8 = (const short8*)Bf;
  f32x4 acc[8];
#pragma unroll
  for (int f = 0; f < 8; ++f) acc[f] = (f32x4){0.f, 0.f, 0.f, 0.f};

#pragma unroll
  for (int s = 0; s < 4; ++s){
    const float* xp = X + (size_t)rload * 128 + 32 * s + 8 * lk;
    float4 xa = *(const float4*)xp;
    float4 xb = *(const float4*)(xp + 4);
    float xv[8] = {xa.x, xa.y, xa.z, xa.w, xb.x, xb.y, xb.z, xb.w};
    short8 ah, al;
#pragma unroll
    for (int j = 0; j < 8; ++j){
      unsigned short h = f2bf(xv[j]);
      ah[j] = (short)h;
      al[j] = (short)f2bf(xv[j] - bf2f(h));
    }
#pragma unroll
    for (int f = 0; f < 8; ++f){
      short8 bh = B8[((s * 8 + f) * 2 + 0) * 64 + l];
      short8 bl = B8[((s * 8 + f) * 2 + 1) * 64 + l];
      acc[f] = __builtin_amdgcn_mfma_f32_16x16x32_bf16(ah, bh, acc[f], 0, 0, 0);
      acc[f] = __builtin_amdgcn_mfma_f32_16x16x32_bf16(al, bh, acc[f], 0, 0, 0);
      acc[f] = __builtin_amdgcn_mfma_f32_16x16x32_bf16(ah, bl, acc[f], 0, 0, 0);
    }
  }
  // epilogue: C layout col = lane&15, row = 4*(lane>>4)+reg
  float avs[8], avd[8];
#pragma unroll
  for (int f = 0; f < 8; ++f){
    avs[f] = att_src[16 * f + lrow];
    avd[f] = att_dst[16 * f + lrow];
  }
#pragma unroll
  for (int reg = 0; reg < 4; ++reg){
    int row = r0 + 4 * lk + reg;
    if (row < N){
#pragma unroll
      for (int f = 0; f < 8; ++f) Hb[(size_t)row * 128 + 16 * f + lrow] = f2bf(acc[f][reg]);
    }
    float ps0 = 0.f, ps1 = 0.f, pd0 = 0.f, pd1 = 0.f;
#pragma unroll
    for (int f = 0; f < 4; ++f){ ps0 += acc[f][reg] * avs[f]; pd0 += acc[f][reg] * avd[f]; }
#pragma unroll
    for (int f = 4; f < 8; ++f){ ps1 += acc[f][reg] * avs[f]; pd1 += acc[f][reg] * avd[f]; }
#pragma unroll
    for (int off = 1; off < 16; off <<= 1){
      ps0 += __shfl_xor(ps0, off); ps1 += __shfl_xor(ps1, off);
      pd0 += __shfl_xor(pd0, off); pd1 += __shfl_xor(pd1, off);
    }
    if (lrow == 0 && row < N){
      a_s[2 * row] = ps0; a_s[2 * row + 1] = ps1;
      a_d[2 * row] = pd0; a_d[2 * row + 1] = pd1;
    }
  }
}

// ---- dst-CSR build ----------------------------------------------------------
__global__ void k_hist(const int* __restrict__ ei, int* __restrict__ pd, int E){
  int i = blockIdx.x * 256 + threadIdx.x;
  if (i >= E) return;
  atomicAdd(&pd[ei[E + i] + 1], 1);
}

__global__ __launch_bounds__(1024) void k_scan(int* __restrict__ p, int* __restrict__ c, int N){
  __shared__ int sums[1024];
  int t = threadIdx.x;
  int M = N + 1;
  int C = (M + 1023) >> 10;
  int lo = t * C, hi = min(lo + C, M);
  int s = 0;
  for (int i = lo; i < hi; i++) s += p[i];
  sums[t] = s;
  __syncthreads();
  for (int off = 1; off < 1024; off <<= 1){
    int v = (t >= off) ? sums[t - off] : 0;
    __syncthreads();
    sums[t] += v;
    __syncthreads();
  }
  int pre = (t == 0) ? 0 : sums[t - 1];
  for (int i = lo; i < hi; i++){
    pre += p[i];
    p[i] = pre;               // p[i] = start offset of node i ; p[N] = E
    if (i < N) c[i] = pre;    // cursor = start of node i
  }
}

__global__ void k_fill(const int* __restrict__ ei, int* __restrict__ cur, int* __restrict__ adj, int E){
  int i = blockIdx.x * 256 + threadIdx.x;
  if (i >= E) return;
  int s = ei[i], d = ei[E + i];
  int p = atomicAdd(&cur[d], 1);
  adj[p] = s;
}

// ---- edge -> graph id (breaks the ei->batch->ea dependent chain) -----------
__global__ void k_eg(const int* __restrict__ ei, const int* __restrict__ batch,
                     int* __restrict__ eg, int E){
  int i = blockIdx.x * 256 + threadIdx.x;
  if (i < E) eg[i] = batch[ei[i]];
}

// ---- per-dst softmax aggregation, bf16 h, readlane broadcast ---------------
__global__ __launch_bounds__(256) void k_agg(const int* __restrict__ ptr, const int* __restrict__ adj,
                                             const unsigned* __restrict__ Hu,
                                             const float* __restrict__ a_s, const float* __restrict__ a_d,
                                             float* __restrict__ nf, int N){
  int wid = (blockIdx.x * blockDim.x + threadIdx.x) >> 6;
  int l = threadIdx.x & 63;
  if (wid >= N) return;
  int n = wid;
  float2 adn = *(const float2*)&a_d[2 * n];
  float2 asn = *(const float2*)&a_s[2 * n];
  float e0 = lrelu(asn.x + adn.x), e1 = lrelu(asn.y + adn.y);   // self-loop
  int beg = ptr[n], end = ptr[n + 1];
  float lm0 = e0, lm1 = e1;
  for (int i = beg + l; i < end; i += 64){
    int s = adj[i];
    float2 a2 = *(const float2*)&a_s[2 * s];
    lm0 = fmaxf(lm0, lrelu(a2.x + adn.x));
    lm1 = fmaxf(lm1, lrelu(a2.y + adn.y));
  }
#pragma unroll
  for (int off = 32; off >= 1; off >>= 1){
    lm0 = fmaxf(lm0, __shfl_xor(lm0, off));
    lm1 = fmaxf(lm1, __shfl_xor(lm1, off));
  }
  float w0s = __expf(e0 - lm0), w1s = __expf(e1 - lm1);
  unsigned hv = Hu[(size_t)n * 64 + l];
  float wsel = (l < 32) ? w0s : w1s;
  float accA = wsel * bf2f((unsigned short)(hv & 0xffffu));
  float accB = wsel * bf2f((unsigned short)(hv >> 16));
  float dden0 = 0.f, dden1 = 0.f;
  for (int base = beg; base < end; base += 64){
    int idx = base + l;
    int cl = min(end - base, 64);
    int s = adj[min(idx, end - 1)];
    float2 a2 = *(const float2*)&a_s[2 * s];
    float w0 = 0.f, w1 = 0.f;
    if (idx < end){
      w0 = __expf(lrelu(a2.x + adn.x) - lm0);
      w1 = __expf(lrelu(a2.y + adn.y) - lm1);
    }
    dden0 += w0; dden1 += w1;
    int w0i = __float_as_int(w0), w1i = __float_as_int(w1);
#pragma unroll 4
    for (int j = 0; j < cl; ++j){
      int sj = __builtin_amdgcn_readlane(s, j);
      float wj0 = __int_as_float(__builtin_amdgcn_readlane(w0i, j));
      float wj1 = __int_as_float(__builtin_amdgcn_readlane(w1i, j));
      unsigned hvj = Hu[(size_t)sj * 64 + l];
      float wj = (l < 32) ? wj0 : wj1;
      accA += wj * bf2f((unsigned short)(hvj & 0xffffu));
      accB += wj * bf2f((unsigned short)(hvj >> 16));
    }
  }
#pragma unroll
  for (int off = 32; off >= 1; off >>= 1){
    dden0 += __shfl_xor(dden0, off);
    dden1 += __shfl_xor(dden1, off);
  }
  float den = (l < 32) ? (dden0 + w0s) : (dden1 + w1s);
  float2 o; o.x = accA / den; o.y = accB / den;
  *(float2*)&nf[(size_t)n * 128 + 2 * l] = o;
}

// ---- pooled edge_attr sums per graph (block partials in LDS) ---------------
// 512 blocks x 1024 thr (16 waves): 33KB LDS -> 2 blocks/CU -> 32 waves/CU.
// eg[] precomputed: the eg and ea loads are independent (no dependent chain).
__global__ __launch_bounds__(1024) void k_Spool(const int* __restrict__ eg, const float* __restrict__ ea,
                                                float* __restrict__ part, int E){
  __shared__ float loc[256 * 33];
  int t = threadIdx.x;
  for (int i = t; i < 256 * 33; i += 1024) loc[i] = 0.f;
  __syncthreads();
  int l = t & 63, wv = t >> 6;
  int gw = blockIdx.x * SP_WAVES + wv;            // 0..8191
  int per = (E + SP_BLOCKS * SP_WAVES - 1) / (SP_BLOCKS * SP_WAVES);
  int b0 = gw * per, b1 = min(b0 + per, E);
  int d = l & 31;
#pragma unroll 2
  for (int e = b0 + (l >> 5); e < b1; e += 2){
    int g = eg[e];
    float v = ea[(size_t)e * 32 + d];
    atomicAdd(&loc[g * 33 + d], v);
    if (d == 0) atomicAdd(&loc[g * 33 + 32], 1.0f);
  }
  __syncthreads();
  float* dst = part + (size_t)blockIdx.x * (256 * 33);
  for (int i = t; i < 256 * 33; i += 1024) dst[i] = loc[i];
}

__global__ void k_Sred(const float* __restrict__ part, float* __restrict__ pS, float* __restrict__ Eg){
  int g = blockIdx.x, t = threadIdx.x;   // 64 threads
  if (t >= 33) return;
  float s = 0.f;
#pragma unroll 8
  for (int b = 0; b < SP_BLOCKS; ++b) s += part[(size_t)b * (256 * 33) + g * 33 + t];
  if (t < 32) pS[g * 32 + t] = s;
  else Eg[g] = s;
}

// ---- graph boundaries (batch sorted) ---------------------------------------
__global__ void k_gstart(const int* __restrict__ batch, int* __restrict__ gstart, int N, int G){
  int g = threadIdx.x;
  if (g > G) return;
  int lo = 0, hi = N;
  while (lo < hi){
    int mid = (lo + hi) >> 1;
    if (batch[mid] < g) lo = mid + 1; else hi = mid;
  }
  gstart[g] = lo;
}

// ---- fused pool + MLP head --------------------------------------------------
__global__ __launch_bounds__(128) void k_poolhead(const int* __restrict__ gstart, const float* __restrict__ nf,
                                                  const float* __restrict__ pS, const float* __restrict__ Eg,
                                                  const float* __restrict__ b_gat, const float* __restrict__ W_edge,
                                                  const float* __restrict__ b_edge,
                                                  const float* __restrict__ W1, const float* __restrict__ b1,
                                                  const float* __restrict__ W2, const float* __restrict__ b2,
                                                  const float* __restrict__ W3, const float* __restrict__ b3,
                                                  float* __restrict__ out){
  __shared__ float comb[128];
  __shared__ float z1[100];
  __shared__ float z2[32];
  int g = blockIdx.x, t = threadIdx.x;
  int s0 = gstart[g], s1 = gstart[g + 1];
  int cnt = s1 - s0;
  float pool = 0.f;
  for (int n = s0; n < s1; ++n) pool += nf[(size_t)n * 128 + t];
  float dot = 0.f;
#pragma unroll
  for (int k = 0; k < 32; ++k) dot += pS[g * 32 + k] * W_edge[k * 128 + t];
  comb[t] = pool + (float)cnt * b_gat[t] + Eg[g] * b_edge[t] + dot;
  __syncthreads();
  if (t < 100){
    float z = b1[t];
    for (int k = 0; k < 128; ++k) z += comb[k] * W1[k * 100 + t];
    z1[t] = fmaxf(z, 0.f);
  }
  __syncthreads();
  if (t < 25){
    float z = b2[t];
    for (int k = 0; k < 100; ++k) z += z1[k] * W2[k * 25 + t];
    z2[t] = fmaxf(z, 0.f);
  }
  __syncthreads();
  if (t < 2){
    float z = b3[t];
    for (int k = 0; k < 25; ++k) z += z2[k] * W3[k * 2 + t];
    out[g * 2 + t] = z;
  }
}

extern "C" void kernel_launch(void* const* d_in, const int* in_sizes, int n_in,
                              void* d_out, int out_size, void* d_ws, size_t ws_size,
                              hipStream_t stream) {
  const float* x       = (const float*)d_in[0];
  const int*   ei      = (const int*)d_in[1];
  const float* ea      = (const float*)d_in[2];
  const int*   batch   = (const int*)d_in[3];
  const float* W_gat   = (const float*)d_in[4];
  const float* att_src = (const float*)d_in[5];
  const float* att_dst = (const float*)d_in[6];
  const float* b_gat   = (const float*)d_in[7];
  const float* W_edge  = (const float*)d_in[8];
  const float* b_edge  = (const float*)d_in[9];
  const float* W1 = (const float*)d_in[10];
  const float* b1 = (const float*)d_in[11];
  const float* W2 = (const float*)d_in[12];
  const float* b2 = (const float*)d_in[13];
  const float* W3 = (const float*)d_in[14];
  const float* b3 = (const float*)d_in[15];

  int N = in_sizes[3];        // 50000
  int E = in_sizes[1] / 2;    // 1600000
  int G = N_GRAPHS;

  float* ws = (float*)d_ws;
  size_t o = 0;
  unsigned short* Hb = (unsigned short*)(ws + o); o += (size_t)N * 64;   // N*128 bf16
  float* a_s       = ws + o; o += (size_t)N * 2;
  float* a_d       = ws + o; o += (size_t)N * 2;
  float* nf        = ws + o; o += (size_t)N * 128;
  unsigned short* Bf = (unsigned short*)(ws + o); o += 16384;            // 32768 bf16
  int* ptr_dst     = (int*)(ws + o); o += (size_t)(N + 1);
  int* cur_dst     = (int*)(ws + o); o += (size_t)N + 1;
  int* adj         = (int*)(ws + o); o += (size_t)E;
  int* eg          = (int*)(ws + o); o += (size_t)E;
  float* part      = ws + o; o += (size_t)SP_BLOCKS * 256 * 33;
  float* pS        = ws + o; o += (size_t)G * 32;
  float* Eg        = ws + o; o += (size_t)G;
  int* gstart      = (int*)(ws + o); o += (size_t)(G + 1);

  hipMemsetAsync(ptr_dst, 0, (N + 1) * sizeof(int), stream);

  k_prepW<<<128, 256, 0, stream>>>(W_gat, Bf);
  k_gemm<<<(N + 63) / 64, 256, 0, stream>>>(x, Bf, att_src, att_dst, Hb, a_s, a_d, N);
  k_hist<<<(E + 255) / 256, 256, 0, stream>>>(ei, ptr_dst, E);
  k_scan<<<1, 1024, 0, stream>>>(ptr_dst, cur_dst, N);
  k_fill<<<(E + 255) / 256, 256, 0, stream>>>(ei, cur_dst, adj, E);
  k_eg<<<(E + 255) / 256, 256, 0, stream>>>(ei, batch, eg, E);
  k_agg<<<(N + 3) / 4, 256, 0, stream>>>(ptr_dst, adj, (const unsigned*)Hb, a_s, a_d, nf, N);
  k_Spool<<<SP_BLOCKS, 1024, 0, stream>>>(eg, ea, part, E);
  k_Sred<<<G, 64, 0, stream>>>(part, pS, Eg);
  k_gstart<<<1, 512, 0, stream>>>(batch, gstart, N, G);
  k_poolhead<<<G, 128, 0, stream>>>(gstart, nf, pS, Eg, b_gat, W_edge, b_edge,
                                    W1, b1, W2, b2, W3, b3, (float*)d_out);
}